// Round 6
// baseline (1062.608 us; speedup 1.0000x reference)
//
#include <hip/hip_runtime.h>
#include <math.h>

#define B 256
#define N 128
#define E 2048
#define D 512
#define R 1024
#define O 10
#define L 5
#define BK 32

typedef unsigned short u16;
typedef unsigned int u32;
typedef __bf16 bf16x8 __attribute__((ext_vector_type(8)));
typedef u16 u16x8 __attribute__((ext_vector_type(8)));
typedef float floatx4 __attribute__((ext_vector_type(4)));

// ---- bf16 helpers (RNE) ----------------------------------------------------
__device__ inline u16 f2bf(float f) {
    union { float f; u32 u; } v; v.f = f;
    u32 u = v.u;
    return (u16)((u + 0x7fffu + ((u >> 16) & 1u)) >> 16);
}
__device__ inline float bf2f(u16 s) {
    union { u32 u; float f; } v; v.u = ((u32)s) << 16;
    return v.f;
}

__device__ inline float fast_tanh(float x) {
    return 1.0f - 2.0f / (__expf(2.0f * x) + 1.0f);
}

// ---- async global->LDS, 16B per lane (used by aggregate only) --------------
__device__ inline void gload16(const void* g, void* l) {
    __builtin_amdgcn_global_load_lds(
        (const __attribute__((address_space(1))) void*)g,
        (__attribute__((address_space(3))) void*)l, 16, 0, 0);
}

__device__ inline bf16x8 ldsfrag(const u16* p) {
    u16x8 v = *(const u16x8*)p;
    return __builtin_bit_cast(bf16x8, v);
}
__device__ inline bf16x8 gfrag(const u16* p) {
    uint4 v = *(const uint4*)p;
    return __builtin_bit_cast(bf16x8, v);
}

// ---------------------------------------------------------------------------
__global__ void zero_kernel(float* __restrict__ p, size_t n) {
    size_t i = (size_t)blockIdx.x * blockDim.x + threadIdx.x;
    size_t stride = (size_t)gridDim.x * blockDim.x;
    for (; i < n; i += stride) p[i] = 0.f;
}

__global__ void fill_adj_kernel(const int* __restrict__ edges, float* __restrict__ C) {
    int idx = blockIdx.x * blockDim.x + threadIdx.x;
    if (idx >= B * E) return;
    int b = idx / E;
    int e = idx - b * E;
    int src = edges[b * 2 * E + e];
    int dst = edges[b * 2 * E + E + e];
    atomicAdd(&C[(size_t)b * N * N + (size_t)dst * N + src], 1.0f);
}

__global__ void diag_kernel(float* __restrict__ C) {
    int idx = blockIdx.x * blockDim.x + threadIdx.x;
    if (idx >= B * N) return;
    C[(size_t)(idx >> 7) * N * N + (size_t)(idx & 127) * 129] += 1.0f;
}

__global__ void cbf_kernel(const float4* __restrict__ C4, ushort4* __restrict__ o, size_t n4) {
    size_t i = (size_t)blockIdx.x * blockDim.x + threadIdx.x;
    size_t stride = (size_t)gridDim.x * blockDim.x;
    for (; i < n4; i += stride) {
        float4 v = C4[i];
        ushort4 r;
        r.x = f2bf(v.x); r.y = f2bf(v.y); r.z = f2bf(v.z); r.w = f2bf(v.w);
        o[i] = r;
    }
}

// ---------------------------------------------------------------------------
// split x (fp32) -> hi/lo bf16 pair, LINEAR layout [b][n][k]
// ---------------------------------------------------------------------------
__global__ void split_kernel(const float4* __restrict__ x4,
                             uint2* __restrict__ hi4, uint2* __restrict__ lo4, size_t n4) {
    size_t i = (size_t)blockIdx.x * blockDim.x + threadIdx.x;
    size_t stride = (size_t)gridDim.x * blockDim.x;
    for (; i < n4; i += stride) {
        float4 v = x4[i];
        u16 h0 = f2bf(v.x), h1 = f2bf(v.y), h2 = f2bf(v.z), h3 = f2bf(v.w);
        uint2 hp; hp.x = (u32)h0 | ((u32)h1 << 16); hp.y = (u32)h2 | ((u32)h3 << 16);
        hi4[i] = hp;
        u16 l0 = f2bf(v.x - bf2f(h0)), l1 = f2bf(v.y - bf2f(h1));
        u16 l2 = f2bf(v.z - bf2f(h2)), l3 = f2bf(v.w - bf2f(h3));
        uint2 lp; lp.x = (u32)l0 | ((u32)l1 << 16); lp.y = (u32)l2 | ((u32)l3 << 16);
        lo4[i] = lp;
    }
}

// ---------------------------------------------------------------------------
// W_cp[l][0:512][1024] fp32 -> Wp_hi/Wp_lo packed in MFMA B-frag order:
//   W[k][r] -> (((l*64 + (r>>4))*16 + (k>>5))*512 + lane*8 + (k&7)),
//   lane = (r&15) + 16*((k>>3)&3).
// A wave loads a 16r x 32k frag as one coalesced 1KB dwordx4.
// ---------------------------------------------------------------------------
__global__ __launch_bounds__(256)
void wt_split_kernel(const float* __restrict__ W_cp,
                     u16* __restrict__ Wp_hi, u16* __restrict__ Wp_lo) {
    __shared__ float t[64][65];
    const int l = blockIdx.z, k0 = blockIdx.y * 64, r0 = blockIdx.x * 64;
    const float* Wl = W_cp + (size_t)l * 513 * 1024;
    const int tx = threadIdx.x & 63, ty = threadIdx.x >> 6;
#pragma unroll
    for (int p = 0; p < 16; ++p) {
        int k = ty + p * 4;
        t[k][tx] = Wl[(size_t)(k0 + k) * 1024 + r0 + tx];
    }
    __syncthreads();
    // 512 slots per 64x64 tile: slot = (r16t*2 + kst)*64 + lane
#pragma unroll
    for (int p = 0; p < 2; ++p) {
        const int slot = threadIdx.x * 2 + p;
        const int lane = slot & 63;
        const int kst  = (slot >> 6) & 1;
        const int r16t = slot >> 7;
        const int rin  = r16t * 16 + (lane & 15);
        const int kin  = kst * 32 + (lane >> 4) * 8;
        u16 hv[8], lv[8];
#pragma unroll
        for (int j = 0; j < 8; ++j) {
            float v = t[kin + j][rin];
            hv[j] = f2bf(v);
            lv[j] = f2bf(v - bf2f(hv[j]));
        }
        const int rg = (r0 >> 4) + r16t;
        const int ks = (k0 >> 5) + kst;
        size_t base = (((size_t)l * 64 + rg) * 16 + ks) * 512 + (size_t)lane * 8;
        *(uint4*)(Wp_hi + base) = *(const uint4*)hv;
        *(uint4*)(Wp_lo + base) = *(const uint4*)lv;
    }
}

// ---------------------------------------------------------------------------
// cp_pool, barrier-free all-register K-loop.
// Wave-private: A-frags from linear h (4-lane 64B segments), B-frags from
// frag-packed W (1KB coalesced). Double-buffered in VGPRs; no __syncthreads
// in the loop -> per-wave vmcnt scheduling only, waves free-run.
// ---------------------------------------------------------------------------
__global__ __launch_bounds__(256)
void cp_pool_mfma_kernel(const u16* __restrict__ h_hi, const u16* __restrict__ h_lo,
                         const u16* __restrict__ Wp_hi, const u16* __restrict__ Wp_lo,
                         const float* __restrict__ Wbias,   // [1024] fp32 (W row 512)
                         float* __restrict__ prod_out)      // [B][R] this layer
{
    __shared__ float red[2][128];

    const int flat = blockIdx.x;
    const int s    = flat >> 3;
    const int b    = (flat & 7) * 32 + (s >> 3);
    const int r0   = (s & 7) * 128;

    const int tid  = threadIdx.x;
    const int w    = tid >> 6;
    const int lane = tid & 63;
    const int rb   = w & 1;
    const int cb   = w >> 1;

    floatx4 acc[4][4];
#pragma unroll
    for (int i = 0; i < 4; ++i)
#pragma unroll
        for (int j = 0; j < 4; ++j)
#pragma unroll
            for (int k = 0; k < 4; ++k) acc[i][j][k] = 0.f;

    // A: linear h, frag t at row rb*64 + t*16 + (lane&15), k = ks*32 + (lane>>4)*8
    const size_t aOff = ((size_t)b * 128 + rb * 64 + (lane & 15)) * 512 + ((lane >> 4) * 8);
    // B: packed W, frag t at r-group (s&7)*8 + cb*4 + t, step ks
    const size_t bOff = (((size_t)((s & 7) * 8 + cb * 4)) * 16) * 512 + (size_t)lane * 8;

    bf16x8 Ah[2][4], Al[2][4], Bh[2][4], Bl[2][4];

#define LOADSTEP(ks, p)                                                        \
    {                                                                          \
        _Pragma("unroll")                                                      \
        for (int t = 0; t < 4; ++t) {                                          \
            const size_t ao = aOff + (size_t)t * 8192 + (size_t)(ks) * 32;     \
            Ah[p][t] = gfrag(h_hi + ao);                                       \
            Al[p][t] = gfrag(h_lo + ao);                                       \
            const size_t bo = bOff + (size_t)t * 8192 + (size_t)(ks) * 512;    \
            Bh[p][t] = gfrag(Wp_hi + bo);                                      \
            Bl[p][t] = gfrag(Wp_lo + bo);                                      \
        }                                                                      \
    }

#define MFMASTEP(p)                                                            \
    {                                                                          \
        _Pragma("unroll")                                                      \
        for (int i = 0; i < 4; ++i)                                            \
            _Pragma("unroll")                                                  \
            for (int j = 0; j < 4; ++j) {                                      \
                acc[i][j] = __builtin_amdgcn_mfma_f32_16x16x32_bf16(           \
                    Al[p][i], Bh[p][j], acc[i][j], 0, 0, 0);                   \
                acc[i][j] = __builtin_amdgcn_mfma_f32_16x16x32_bf16(           \
                    Ah[p][i], Bl[p][j], acc[i][j], 0, 0, 0);                   \
                acc[i][j] = __builtin_amdgcn_mfma_f32_16x16x32_bf16(           \
                    Ah[p][i], Bh[p][j], acc[i][j], 0, 0, 0);                   \
            }                                                                  \
    }

    LOADSTEP(0, 0)
    LOADSTEP(1, 1)
#pragma unroll
    for (int ks = 0; ks < 16; ks += 2) {
        MFMASTEP(0)
        if (ks + 2 < 16) LOADSTEP(ks + 2, 0)
        MFMASTEP(1)
        if (ks + 3 < 16) LOADSTEP(ks + 3, 1)
    }
#undef LOADSTEP
#undef MFMASTEP

    // epilogue: +bias, tanh, product over n
    const int quad = lane >> 4;
    const int c16  = lane & 15;
#pragma unroll
    for (int tj = 0; tj < 4; ++tj) {
        const int c = cb * 64 + tj * 16 + c16;
        const float bias = Wbias[r0 + c];
        float p = 1.f;
#pragma unroll
        for (int ti = 0; ti < 4; ++ti)
#pragma unroll
            for (int ri = 0; ri < 4; ++ri)
                p *= fast_tanh(acc[ti][tj][ri] + bias);
        p *= __shfl_xor(p, 16, 64);
        p *= __shfl_xor(p, 32, 64);
        if (quad == 0) red[rb][c] = p;
    }
    __syncthreads();
    if (tid < 128)
        prod_out[(size_t)b * R + r0 + tid] = red[0][tid] * red[1][tid];
}

// ---------------------------------------------------------------------------
// aggregate via MFMA: h_out = (C+I) @ h, LINEAR bf16 hi/lo in/out (round-4).
// ---------------------------------------------------------------------------
__global__ __launch_bounds__(256)
void aggregate_mfma_kernel(const u16* __restrict__ hi_in, const u16* __restrict__ lo_in,
                           const u16* __restrict__ Cbf,    // [B][128][128] bf16 (C+I)
                           u16* __restrict__ hi_out, u16* __restrict__ lo_out)
{
    __shared__ u16 Cs[128 * 32];
    __shared__ u16 Bs_hi[128 * 40];       // [d][s], stride 40
    __shared__ u16 Bs_lo[128 * 40];

    const int flat = blockIdx.x;
    const int rest = flat >> 3;
    const int b    = (flat & 7) * 32 + (rest >> 2);
    const int d0   = (rest & 3) * 128;

    const int tid  = threadIdx.x;
    const int w    = tid >> 6;
    const int lane = tid & 63;
    const int rb   = w & 1;
    const int cb   = w >> 1;

    floatx4 acc[4][4];
#pragma unroll
    for (int i = 0; i < 4; ++i)
#pragma unroll
        for (int j = 0; j < 4; ++j)
#pragma unroll
            for (int k = 0; k < 4; ++k) acc[i][j][k] = 0.f;

    const int kswz = (((lane & 3) ^ ((lane >> 3) & 3)) * 8);
    const u16* gC = Cbf + ((size_t)b * 128 + (w * 32 + (lane >> 2))) * 128 + kswz;

    const int ssi = tid >> 3;           // 0..31 (s within chunk)
    const int dg  = (tid & 7) * 16;     // 0..112
    const u16* gBh = hi_in + ((size_t)b * 128 + ssi) * 512 + d0 + dg;
    const u16* gBl = lo_in + ((size_t)b * 128 + ssi) * 512 + d0 + dg;

    const int am  = rb * 64 + (lane & 15);
    const int ko  = (((lane >> 4) ^ ((lane >> 1) & 3)) * 8);
    const int bko = (lane >> 4) * 8;

    for (int s0 = 0; s0 < 128; s0 += 32) {
#pragma unroll
        for (int it = 0; it < 2; ++it)
            gload16(gC + s0 + (size_t)it * 16 * 128, Cs + (w * 2 + it) * 512);

        {
            const u16* ph = gBh + (size_t)s0 * 512;
            const u16* pl = gBl + (size_t)s0 * 512;
            uint4 a0 = *(const uint4*)ph;
            uint4 a1 = *(const uint4*)(ph + 8);
            uint4 b0 = *(const uint4*)pl;
            uint4 b1 = *(const uint4*)(pl + 8);
            const u16* av0 = (const u16*)&a0; const u16* av1 = (const u16*)&a1;
            const u16* bv0 = (const u16*)&b0; const u16* bv1 = (const u16*)&b1;
#pragma unroll
            for (int i = 0; i < 8; ++i) {
                Bs_hi[(dg + i) * 40 + ssi]     = av0[i];
                Bs_hi[(dg + 8 + i) * 40 + ssi] = av1[i];
                Bs_lo[(dg + i) * 40 + ssi]     = bv0[i];
                Bs_lo[(dg + 8 + i) * 40 + ssi] = bv1[i];
            }
        }
        __syncthreads();

        bf16x8 af[4], bhf[4], blf[4];
#pragma unroll
        for (int t = 0; t < 4; ++t) {
            af[t]  = ldsfrag(&Cs[(am + t * 16) * 32 + ko]);
            const int d = cb * 64 + t * 16 + (lane & 15);
            bhf[t] = ldsfrag(&Bs_hi[d * 40 + bko]);
            blf[t] = ldsfrag(&Bs_lo[d * 40 + bko]);
        }
#pragma unroll
        for (int i = 0; i < 4; ++i)
#pragma unroll
            for (int j = 0; j < 4; ++j) {
                acc[i][j] = __builtin_amdgcn_mfma_f32_16x16x32_bf16(af[i], bhf[j], acc[i][j], 0, 0, 0);
                acc[i][j] = __builtin_amdgcn_mfma_f32_16x16x32_bf16(af[i], blf[j], acc[i][j], 0, 0, 0);
            }
        __syncthreads();
    }

    const int quad = lane >> 4;
    const int c16  = lane & 15;
#pragma unroll
    for (int i = 0; i < 4; ++i)
#pragma unroll
        for (int j = 0; j < 4; ++j) {
            const int d = d0 + cb * 64 + j * 16 + c16;
#pragma unroll
            for (int ri = 0; ri < 4; ++ri) {
                const int n = rb * 64 + i * 16 + quad * 4 + ri;
                size_t o = ((size_t)b * 128 + n) * 512 + d;
                float v = acc[i][j][ri];
                u16 hv = f2bf(v);
                hi_out[o] = hv;
                lo_out[o] = f2bf(v - bf2f(hv));
            }
        }
}

// ---------------------------------------------------------------------------
__global__ __launch_bounds__(256)
void score_kernel(const float* __restrict__ prod,   // [L,B,R]
                  const float* __restrict__ lin_w,  // [L,R,O]
                  const float* __restrict__ lin_b,  // [L,O]
                  float* __restrict__ out)          // [B,O]
{
    const int b   = blockIdx.x;
    const int tid = threadIdx.x;

    float acc[O];
#pragma unroll
    for (int o = 0; o < O; ++o) acc[o] = 0.f;

    for (int l = 0; l < L; ++l) {
        const float* pl = prod + ((size_t)l * B + b) * R;
        const float* wl = lin_w + (size_t)l * R * O;
        for (int r = tid; r < R; r += 256) {
            const float p = pl[r];
#pragma unroll
            for (int o = 0; o < O; ++o)
                acc[o] = fmaf(p, wl[r * O + o], acc[o]);
        }
    }

    __shared__ float sb[256];
    for (int o = 0; o < O; ++o) {
        sb[tid] = acc[o];
        __syncthreads();
        for (int off = 128; off > 0; off >>= 1) {
            if (tid < off) sb[tid] += sb[tid + off];
            __syncthreads();
        }
        if (tid == 0) {
            float bias = 0.f;
            for (int l = 0; l < L; ++l) bias += lin_b[l * O + o];
            out[b * O + o] = sb[0] + bias;
        }
        __syncthreads();
    }
}

// ---------------------------------------------------------------------------
extern "C" void kernel_launch(void* const* d_in, const int* in_sizes, int n_in,
                              void* d_out, int out_size, void* d_ws, size_t ws_size,
                              hipStream_t stream) {
    const float* x     = (const float*)d_in[0];   // [B,N,D]
    const int*   edges = (const int*)d_in[1];     // [B,2,E]
    const float* W_cp  = (const float*)d_in[2];   // [L,513,1024]
    const float* lin_w = (const float*)d_in[3];   // [L,R,O]
    const float* lin_b = (const float*)d_in[4];   // [L,O]
    float*       out   = (float*)d_out;           // [B,O]

    char* ws = (char*)d_ws;
    const size_t C_BYTES   = (size_t)B * N * N * 4;        // 16.8 MB
    const size_t CBF_BYTES = (size_t)B * N * N * 2;        // 8.4 MB
    const size_t HH_BYTES  = (size_t)B * N * D * 2;        // 33.6 MB
    const size_t WP_BYTES  = (size_t)L * 64 * 16 * 512 * 2;// 5.24 MB

    float* C     = (float*)ws;                    ws += C_BYTES;
    u16*   Cbf   = (u16*)ws;                      ws += CBF_BYTES;
    u16*   hiA   = (u16*)ws;                      ws += HH_BYTES;
    u16*   loA   = (u16*)ws;                      ws += HH_BYTES;
    u16*   hiB   = (u16*)ws;                      ws += HH_BYTES;
    u16*   loB   = (u16*)ws;                      ws += HH_BYTES;
    u16*   Wp_hi = (u16*)ws;                      ws += WP_BYTES;
    u16*   Wp_lo = (u16*)ws;                      ws += WP_BYTES;
    float* prod  = (float*)ws;                    // [L,B,R] 5.24 MB

    zero_kernel<<<1024, 256, 0, stream>>>(C, (size_t)B * N * N);
    fill_adj_kernel<<<(B * E + 255) / 256, 256, 0, stream>>>(edges, C);
    diag_kernel<<<(B * N + 255) / 256, 256, 0, stream>>>(C);
    cbf_kernel<<<1024, 256, 0, stream>>>((const float4*)C, (ushort4*)Cbf,
                                         (size_t)B * N * N / 4);
    wt_split_kernel<<<dim3(16, 8, L), 256, 0, stream>>>(W_cp, Wp_hi, Wp_lo);
    split_kernel<<<2048, 256, 0, stream>>>((const float4*)x, (uint2*)hiA, (uint2*)loA,
                                           (size_t)B * N * D / 4);

    const size_t WP_L = (size_t)64 * 16 * 512;    // per-layer stride (u16)

    // layer 0
    cp_pool_mfma_kernel<<<2048, 256, 0, stream>>>(
        hiA, loA, Wp_hi, Wp_lo, W_cp + (size_t)512 * 1024, prod);

    const u16* phi = hiA; const u16* plo = loA;
    u16* bhi[2] = {hiB, hiA};
    u16* blo[2] = {loB, loA};
    for (int l = 1; l < L; ++l) {
        u16* nhi = bhi[(l - 1) & 1];
        u16* nlo = blo[(l - 1) & 1];
        aggregate_mfma_kernel<<<1024, 256, 0, stream>>>(phi, plo, Cbf, nhi, nlo);
        cp_pool_mfma_kernel<<<2048, 256, 0, stream>>>(
            nhi, nlo,
            Wp_hi + (size_t)l * WP_L, Wp_lo + (size_t)l * WP_L,
            W_cp + ((size_t)l * 513 + 512) * 1024,
            prod + (size_t)l * B * R);
        phi = nhi; plo = nlo;
    }

    score_kernel<<<B, 256, 0, stream>>>(prod, lin_w, lin_b, out);
}

// Round 7
// 826.101 us; speedup vs baseline: 1.2863x; 1.2863x over previous
//
#include <hip/hip_runtime.h>
#include <math.h>

#define B 256
#define N 128
#define E 2048
#define D 512
#define R 1024
#define O 10
#define L 5
#define BK 32

typedef unsigned short u16;
typedef unsigned int u32;
typedef __bf16 bf16x8 __attribute__((ext_vector_type(8)));
typedef u16 u16x8 __attribute__((ext_vector_type(8)));
typedef float floatx4 __attribute__((ext_vector_type(4)));

// ---- bf16 helpers (RNE) ----------------------------------------------------
__device__ inline u16 f2bf(float f) {
    union { float f; u32 u; } v; v.f = f;
    u32 u = v.u;
    return (u16)((u + 0x7fffu + ((u >> 16) & 1u)) >> 16);
}
__device__ inline float bf2f(u16 s) {
    union { u32 u; float f; } v; v.u = ((u32)s) << 16;
    return v.f;
}

__device__ inline float fast_tanh(float x) {
    return 1.0f - 2.0f / (__expf(2.0f * x) + 1.0f);
}

// ---- async global->LDS, 16B per lane (aggregate only) ----------------------
__device__ inline void gload16(const void* g, void* l) {
    __builtin_amdgcn_global_load_lds(
        (const __attribute__((address_space(1))) void*)g,
        (__attribute__((address_space(3))) void*)l, 16, 0, 0);
}

__device__ inline bf16x8 ldsfrag(const u16* p) {
    u16x8 v = *(const u16x8*)p;
    return __builtin_bit_cast(bf16x8, v);
}

// ---------------------------------------------------------------------------
__global__ void zero_kernel(float* __restrict__ p, size_t n) {
    size_t i = (size_t)blockIdx.x * blockDim.x + threadIdx.x;
    size_t stride = (size_t)gridDim.x * blockDim.x;
    for (; i < n; i += stride) p[i] = 0.f;
}

__global__ void fill_adj_kernel(const int* __restrict__ edges, float* __restrict__ C) {
    int idx = blockIdx.x * blockDim.x + threadIdx.x;
    if (idx >= B * E) return;
    int b = idx / E;
    int e = idx - b * E;
    int src = edges[b * 2 * E + e];
    int dst = edges[b * 2 * E + E + e];
    atomicAdd(&C[(size_t)b * N * N + (size_t)dst * N + src], 1.0f);
}

__global__ void diag_kernel(float* __restrict__ C) {
    int idx = blockIdx.x * blockDim.x + threadIdx.x;
    if (idx >= B * N) return;
    C[(size_t)(idx >> 7) * N * N + (size_t)(idx & 127) * 129] += 1.0f;
}

__global__ void cbf_kernel(const float4* __restrict__ C4, ushort4* __restrict__ o, size_t n4) {
    size_t i = (size_t)blockIdx.x * blockDim.x + threadIdx.x;
    size_t stride = (size_t)gridDim.x * blockDim.x;
    for (; i < n4; i += stride) {
        float4 v = C4[i];
        ushort4 r;
        r.x = f2bf(v.x); r.y = f2bf(v.y); r.z = f2bf(v.z); r.w = f2bf(v.w);
        o[i] = r;
    }
}

// ---------------------------------------------------------------------------
// split x (fp32) -> hi/lo bf16 pair, LINEAR layout [b][n][k]
// ---------------------------------------------------------------------------
__global__ void split_kernel(const float4* __restrict__ x4,
                             uint2* __restrict__ hi4, uint2* __restrict__ lo4, size_t n4) {
    size_t i = (size_t)blockIdx.x * blockDim.x + threadIdx.x;
    size_t stride = (size_t)gridDim.x * blockDim.x;
    for (; i < n4; i += stride) {
        float4 v = x4[i];
        u16 h0 = f2bf(v.x), h1 = f2bf(v.y), h2 = f2bf(v.z), h3 = f2bf(v.w);
        uint2 hp; hp.x = (u32)h0 | ((u32)h1 << 16); hp.y = (u32)h2 | ((u32)h3 << 16);
        hi4[i] = hp;
        u16 l0 = f2bf(v.x - bf2f(h0)), l1 = f2bf(v.y - bf2f(h1));
        u16 l2 = f2bf(v.z - bf2f(h2)), l3 = f2bf(v.w - bf2f(h3));
        uint2 lp; lp.x = (u32)l0 | ((u32)l1 << 16); lp.y = (u32)l2 | ((u32)l3 << 16);
        lo4[i] = lp;
    }
}

// ---------------------------------------------------------------------------
// transpose+split W_cp[l][0:512][1024] fp32 -> Wt_hi/Wt_lo [l][1024 r][512 k]
// ---------------------------------------------------------------------------
__global__ __launch_bounds__(256)
void wt_split_kernel(const float* __restrict__ W_cp,
                     u16* __restrict__ Wt_hi, u16* __restrict__ Wt_lo) {
    __shared__ float t[64][65];
    const int l = blockIdx.z, k0 = blockIdx.y * 64, r0 = blockIdx.x * 64;
    const float* Wl = W_cp + (size_t)l * 513 * 1024;
    const int tx = threadIdx.x & 63, ty = threadIdx.x >> 6;
#pragma unroll
    for (int p = 0; p < 16; ++p) {
        int k = ty + p * 4;
        t[k][tx] = Wl[(size_t)(k0 + k) * 1024 + r0 + tx];
    }
    __syncthreads();
    u16* oh = Wt_hi + ((size_t)l * 1024 + r0) * 512 + k0;
    u16* ol = Wt_lo + ((size_t)l * 1024 + r0) * 512 + k0;
#pragma unroll
    for (int p = 0; p < 16; ++p) {
        int r = ty + p * 4;
        float v = t[tx][r];
        u16 hv = f2bf(v);
        oh[(size_t)r * 512 + tx] = hv;
        ol[(size_t)r * 512 + tx] = f2bf(v - bf2f(hv));
    }
}

// ---------------------------------------------------------------------------
// cp_pool via split-bf16 MFMA, register-staged software pipeline:
// per step: B1 -> issue next step's 8 global uint4 loads (regs, full-step
// window) -> ds_read frags -> B2 -> 48-MFMA burst -> ds_write regs -> B1...
// vmcnt waits land after the burst; barrier drains are lgkm-only (cheap).
// Staging map: thread t stages LDS slot sigma=(row=t>>2, chunk c=t&3) and
// sigma+256 (row+64); slot (r,c) holds global chunk c ^ ((r>>1)&3) -> reads
// use r4's proven conflict-free ko; writes are 2-way max; global 256B/16-lane.
// ---------------------------------------------------------------------------
__global__ __launch_bounds__(256)
void cp_pool_mfma_kernel(const u16* __restrict__ h_hi, const u16* __restrict__ h_lo,
                         const u16* __restrict__ Wt_hi, const u16* __restrict__ Wt_lo,
                         const float* __restrict__ Wbias,   // [1024] fp32 (W row 512)
                         float* __restrict__ prod_out)      // [B][R] this layer
{
    __shared__ u16 As_hi[128 * BK], As_lo[128 * BK];
    __shared__ u16 Bs_hi[128 * BK], Bs_lo[128 * BK];
    __shared__ float red[2][128];

    const int flat = blockIdx.x;
    const int s    = flat >> 3;
    const int b    = (flat & 7) * 32 + (s >> 3);
    const int r0   = (s & 7) * 128;

    const int tid  = threadIdx.x;
    const int w    = tid >> 6;
    const int lane = tid & 63;
    const int rb   = w & 1;
    const int cb   = w >> 1;

    floatx4 acc[4][4];
#pragma unroll
    for (int i = 0; i < 4; ++i)
#pragma unroll
        for (int j = 0; j < 4; ++j)
#pragma unroll
            for (int k = 0; k < 4; ++k) acc[i][j][k] = 0.f;

    // staging addressing
    const int row1 = tid >> 2;                       // 0..63
    const int c8   = (tid & 3) * 8;                  // LDS chunk offset
    const int g8   = ((tid & 3) ^ ((tid >> 3) & 3)) * 8;  // global chunk (xor swz)
    const u16* sAh1 = h_hi  + ((size_t)b * 128 + row1) * 512 + g8;
    const u16* sAh2 = sAh1 + (size_t)64 * 512;
    const u16* sAl1 = h_lo  + ((size_t)b * 128 + row1) * 512 + g8;
    const u16* sAl2 = sAl1 + (size_t)64 * 512;
    const u16* sBh1 = Wt_hi + ((size_t)(r0 + row1)) * 512 + g8;
    const u16* sBh2 = sBh1 + (size_t)64 * 512;
    const u16* sBl1 = Wt_lo + ((size_t)(r0 + row1)) * 512 + g8;
    const u16* sBl2 = sBl1 + (size_t)64 * 512;
    u16* wAh1 = As_hi + row1 * 32 + c8;  u16* wAh2 = wAh1 + 64 * 32;
    u16* wAl1 = As_lo + row1 * 32 + c8;  u16* wAl2 = wAl1 + 64 * 32;
    u16* wBh1 = Bs_hi + row1 * 32 + c8;  u16* wBh2 = wBh1 + 64 * 32;
    u16* wBl1 = Bs_lo + row1 * 32 + c8;  u16* wBl2 = wBl1 + 64 * 32;

    const int am = rb * 64 + (lane & 15);
    const int bn = cb * 64 + (lane & 15);
    const int ko = (((lane >> 4) ^ ((lane >> 1) & 3)) * 8);

    uint4 G0, G1, G2, G3, G4, G5, G6, G7;

#define LOADG(koff)                                                            \
    {                                                                          \
        G0 = *(const uint4*)(sAh1 + (koff)); G1 = *(const uint4*)(sAh2 + (koff)); \
        G2 = *(const uint4*)(sAl1 + (koff)); G3 = *(const uint4*)(sAl2 + (koff)); \
        G4 = *(const uint4*)(sBh1 + (koff)); G5 = *(const uint4*)(sBh2 + (koff)); \
        G6 = *(const uint4*)(sBl1 + (koff)); G7 = *(const uint4*)(sBl2 + (koff)); \
    }
#define WRITEG()                                                               \
    {                                                                          \
        *(uint4*)wAh1 = G0; *(uint4*)wAh2 = G1;                                \
        *(uint4*)wAl1 = G2; *(uint4*)wAl2 = G3;                                \
        *(uint4*)wBh1 = G4; *(uint4*)wBh2 = G5;                                \
        *(uint4*)wBl1 = G6; *(uint4*)wBl2 = G7;                                \
    }

    // prologue: stage step 0 (latency exposed once)
    LOADG(0)
    WRITEG()

    for (int ks = 0; ks < 16; ++ks) {
        __syncthreads();                 // B1: prev ds_writes visible (lgkm only)

        if (ks < 15) LOADG((ks + 1) * BK)   // early issue: full-step window

        bf16x8 ah[4], al[4], bh[4], bl[4];
#pragma unroll
        for (int t = 0; t < 4; ++t) {
            ah[t] = ldsfrag(&As_hi[(am + t * 16) * BK + ko]);
            al[t] = ldsfrag(&As_lo[(am + t * 16) * BK + ko]);
            bh[t] = ldsfrag(&Bs_hi[(bn + t * 16) * BK + ko]);
            bl[t] = ldsfrag(&Bs_lo[(bn + t * 16) * BK + ko]);
        }
        __syncthreads();                 // B2: all reads done, LDS free

#pragma unroll
        for (int i = 0; i < 4; ++i)
#pragma unroll
            for (int j = 0; j < 4; ++j) {
                acc[i][j] = __builtin_amdgcn_mfma_f32_16x16x32_bf16(al[i], bh[j], acc[i][j], 0, 0, 0);
                acc[i][j] = __builtin_amdgcn_mfma_f32_16x16x32_bf16(ah[i], bl[j], acc[i][j], 0, 0, 0);
                acc[i][j] = __builtin_amdgcn_mfma_f32_16x16x32_bf16(ah[i], bh[j], acc[i][j], 0, 0, 0);
            }

        if (ks < 15) WRITEG()            // vmcnt waits here, covered by burst
    }
#undef LOADG
#undef WRITEG

    // epilogue: +bias, tanh, product over n
    const int quad = lane >> 4;
    const int c16  = lane & 15;
#pragma unroll
    for (int tj = 0; tj < 4; ++tj) {
        const int c = cb * 64 + tj * 16 + c16;
        const float bias = Wbias[r0 + c];
        float p = 1.f;
#pragma unroll
        for (int ti = 0; ti < 4; ++ti)
#pragma unroll
            for (int ri = 0; ri < 4; ++ri)
                p *= fast_tanh(acc[ti][tj][ri] + bias);
        p *= __shfl_xor(p, 16, 64);
        p *= __shfl_xor(p, 32, 64);
        if (quad == 0) red[rb][c] = p;
    }
    __syncthreads();
    if (tid < 128)
        prod_out[(size_t)b * R + r0 + tid] = red[0][tid] * red[1][tid];
}

// ---------------------------------------------------------------------------
// aggregate via MFMA: h_out = (C+I) @ h, LINEAR bf16 hi/lo in/out (round-4).
// ---------------------------------------------------------------------------
__global__ __launch_bounds__(256)
void aggregate_mfma_kernel(const u16* __restrict__ hi_in, const u16* __restrict__ lo_in,
                           const u16* __restrict__ Cbf,    // [B][128][128] bf16 (C+I)
                           u16* __restrict__ hi_out, u16* __restrict__ lo_out)
{
    __shared__ u16 Cs[128 * 32];
    __shared__ u16 Bs_hi[128 * 40];       // [d][s], stride 40
    __shared__ u16 Bs_lo[128 * 40];

    const int flat = blockIdx.x;
    const int rest = flat >> 3;
    const int b    = (flat & 7) * 32 + (rest >> 2);
    const int d0   = (rest & 3) * 128;

    const int tid  = threadIdx.x;
    const int w    = tid >> 6;
    const int lane = tid & 63;
    const int rb   = w & 1;
    const int cb   = w >> 1;

    floatx4 acc[4][4];
#pragma unroll
    for (int i = 0; i < 4; ++i)
#pragma unroll
        for (int j = 0; j < 4; ++j)
#pragma unroll
            for (int k = 0; k < 4; ++k) acc[i][j][k] = 0.f;

    const int kswz = (((lane & 3) ^ ((lane >> 3) & 3)) * 8);
    const u16* gC = Cbf + ((size_t)b * 128 + (w * 32 + (lane >> 2))) * 128 + kswz;

    const int ssi = tid >> 3;           // 0..31 (s within chunk)
    const int dg  = (tid & 7) * 16;     // 0..112
    const u16* gBh = hi_in + ((size_t)b * 128 + ssi) * 512 + d0 + dg;
    const u16* gBl = lo_in + ((size_t)b * 128 + ssi) * 512 + d0 + dg;

    const int am  = rb * 64 + (lane & 15);
    const int ko  = (((lane >> 4) ^ ((lane >> 1) & 3)) * 8);
    const int bko = (lane >> 4) * 8;

    for (int s0 = 0; s0 < 128; s0 += 32) {
#pragma unroll
        for (int it = 0; it < 2; ++it)
            gload16(gC + s0 + (size_t)it * 16 * 128, Cs + (w * 2 + it) * 512);

        {
            const u16* ph = gBh + (size_t)s0 * 512;
            const u16* pl = gBl + (size_t)s0 * 512;
            uint4 a0 = *(const uint4*)ph;
            uint4 a1 = *(const uint4*)(ph + 8);
            uint4 b0 = *(const uint4*)pl;
            uint4 b1 = *(const uint4*)(pl + 8);
            const u16* av0 = (const u16*)&a0; const u16* av1 = (const u16*)&a1;
            const u16* bv0 = (const u16*)&b0; const u16* bv1 = (const u16*)&b1;
#pragma unroll
            for (int i = 0; i < 8; ++i) {
                Bs_hi[(dg + i) * 40 + ssi]     = av0[i];
                Bs_hi[(dg + 8 + i) * 40 + ssi] = av1[i];
                Bs_lo[(dg + i) * 40 + ssi]     = bv0[i];
                Bs_lo[(dg + 8 + i) * 40 + ssi] = bv1[i];
            }
        }
        __syncthreads();

        bf16x8 af[4], bhf[4], blf[4];
#pragma unroll
        for (int t = 0; t < 4; ++t) {
            af[t]  = ldsfrag(&Cs[(am + t * 16) * 32 + ko]);
            const int d = cb * 64 + t * 16 + (lane & 15);
            bhf[t] = ldsfrag(&Bs_hi[d * 40 + bko]);
            blf[t] = ldsfrag(&Bs_lo[d * 40 + bko]);
        }
#pragma unroll
        for (int i = 0; i < 4; ++i)
#pragma unroll
            for (int j = 0; j < 4; ++j) {
                acc[i][j] = __builtin_amdgcn_mfma_f32_16x16x32_bf16(af[i], bhf[j], acc[i][j], 0, 0, 0);
                acc[i][j] = __builtin_amdgcn_mfma_f32_16x16x32_bf16(af[i], blf[j], acc[i][j], 0, 0, 0);
            }
        __syncthreads();
    }

    const int quad = lane >> 4;
    const int c16  = lane & 15;
#pragma unroll
    for (int i = 0; i < 4; ++i)
#pragma unroll
        for (int j = 0; j < 4; ++j) {
            const int d = d0 + cb * 64 + j * 16 + c16;
#pragma unroll
            for (int ri = 0; ri < 4; ++ri) {
                const int n = rb * 64 + i * 16 + quad * 4 + ri;
                size_t o = ((size_t)b * 128 + n) * 512 + d;
                float v = acc[i][j][ri];
                u16 hv = f2bf(v);
                hi_out[o] = hv;
                lo_out[o] = f2bf(v - bf2f(hv));
            }
        }
}

// ---------------------------------------------------------------------------
__global__ __launch_bounds__(256)
void score_kernel(const float* __restrict__ prod,   // [L,B,R]
                  const float* __restrict__ lin_w,  // [L,R,O]
                  const float* __restrict__ lin_b,  // [L,O]
                  float* __restrict__ out)          // [B,O]
{
    const int b   = blockIdx.x;
    const int tid = threadIdx.x;

    float acc[O];
#pragma unroll
    for (int o = 0; o < O; ++o) acc[o] = 0.f;

    for (int l = 0; l < L; ++l) {
        const float* pl = prod + ((size_t)l * B + b) * R;
        const float* wl = lin_w + (size_t)l * R * O;
        for (int r = tid; r < R; r += 256) {
            const float p = pl[r];
#pragma unroll
            for (int o = 0; o < O; ++o)
                acc[o] = fmaf(p, wl[r * O + o], acc[o]);
        }
    }

    __shared__ float sb[256];
    for (int o = 0; o < O; ++o) {
        sb[tid] = acc[o];
        __syncthreads();
        for (int off = 128; off > 0; off >>= 1) {
            if (tid < off) sb[tid] += sb[tid + off];
            __syncthreads();
        }
        if (tid == 0) {
            float bias = 0.f;
            for (int l = 0; l < L; ++l) bias += lin_b[l * O + o];
            out[b * O + o] = sb[0] + bias;
        }
        __syncthreads();
    }
}

// ---------------------------------------------------------------------------
extern "C" void kernel_launch(void* const* d_in, const int* in_sizes, int n_in,
                              void* d_out, int out_size, void* d_ws, size_t ws_size,
                              hipStream_t stream) {
    const float* x     = (const float*)d_in[0];   // [B,N,D]
    const int*   edges = (const int*)d_in[1];     // [B,2,E]
    const float* W_cp  = (const float*)d_in[2];   // [L,513,1024]
    const float* lin_w = (const float*)d_in[3];   // [L,R,O]
    const float* lin_b = (const float*)d_in[4];   // [L,O]
    float*       out   = (float*)d_out;           // [B,O]

    char* ws = (char*)d_ws;
    const size_t C_BYTES   = (size_t)B * N * N * 4;        // 16.8 MB
    const size_t CBF_BYTES = (size_t)B * N * N * 2;        // 8.4 MB
    const size_t HH_BYTES  = (size_t)B * N * D * 2;        // 33.6 MB
    const size_t WT_BYTES  = (size_t)L * 1024 * 512 * 2;   // 5.24 MB

    float* C     = (float*)ws;                    ws += C_BYTES;
    u16*   Cbf   = (u16*)ws;                      ws += CBF_BYTES;
    u16*   hiA   = (u16*)ws;                      ws += HH_BYTES;
    u16*   loA   = (u16*)ws;                      ws += HH_BYTES;
    u16*   hiB   = (u16*)ws;                      ws += HH_BYTES;
    u16*   loB   = (u16*)ws;                      ws += HH_BYTES;
    u16*   Wt_hi = (u16*)ws;                      ws += WT_BYTES;
    u16*   Wt_lo = (u16*)ws;                      ws += WT_BYTES;
    float* prod  = (float*)ws;                    // [L,B,R] 5.24 MB

    zero_kernel<<<1024, 256, 0, stream>>>(C, (size_t)B * N * N);
    fill_adj_kernel<<<(B * E + 255) / 256, 256, 0, stream>>>(edges, C);
    diag_kernel<<<(B * N + 255) / 256, 256, 0, stream>>>(C);
    cbf_kernel<<<1024, 256, 0, stream>>>((const float4*)C, (ushort4*)Cbf,
                                         (size_t)B * N * N / 4);
    wt_split_kernel<<<dim3(16, 8, L), 256, 0, stream>>>(W_cp, Wt_hi, Wt_lo);
    split_kernel<<<2048, 256, 0, stream>>>((const float4*)x, (uint2*)hiA, (uint2*)loA,
                                           (size_t)B * N * D / 4);

    // layer 0
    cp_pool_mfma_kernel<<<2048, 256, 0, stream>>>(
        hiA, loA, Wt_hi, Wt_lo, W_cp + (size_t)512 * 1024, prod);

    const u16* phi = hiA; const u16* plo = loA;
    u16* bhi[2] = {hiB, hiA};
    u16* blo[2] = {loB, loA};
    for (int l = 1; l < L; ++l) {
        u16* nhi = bhi[(l - 1) & 1];
        u16* nlo = blo[(l - 1) & 1];
        aggregate_mfma_kernel<<<1024, 256, 0, stream>>>(phi, plo, Cbf, nhi, nlo);
        cp_pool_mfma_kernel<<<2048, 256, 0, stream>>>(
            nhi, nlo,
            Wt_hi + (size_t)l * 1024 * 512, Wt_lo + (size_t)l * 1024 * 512,
            W_cp + ((size_t)l * 513 + 512) * 1024,
            prod + (size_t)l * B * R);
        phi = nhi; plo = nlo;
    }

    score_kernel<<<B, 256, 0, stream>>>(prod, lin_w, lin_b, out);
}

// Round 8
// 748.083 us; speedup vs baseline: 1.4204x; 1.1043x over previous
//
#include <hip/hip_runtime.h>
#include <math.h>

#define B 256
#define N 128
#define E 2048
#define D 512
#define R 1024
#define O 10
#define L 5
#define BK 32

typedef unsigned short u16;
typedef unsigned int u32;
typedef __bf16 bf16x8 __attribute__((ext_vector_type(8)));
typedef u16 u16x8 __attribute__((ext_vector_type(8)));
typedef float floatx4 __attribute__((ext_vector_type(4)));

// ---- bf16 helpers (RNE) ----------------------------------------------------
__device__ inline u16 f2bf(float f) {
    union { float f; u32 u; } v; v.f = f;
    u32 u = v.u;
    return (u16)((u + 0x7fffu + ((u >> 16) & 1u)) >> 16);
}
__device__ inline float bf2f(u16 s) {
    union { u32 u; float f; } v; v.u = ((u32)s) << 16;
    return v.f;
}

__device__ inline float fast_tanh(float x) {
    return 1.0f - 2.0f / (__expf(2.0f * x) + 1.0f);
}

// ---- async global->LDS, 16B per lane ---------------------------------------
__device__ inline void gload16(const void* g, void* l) {
    __builtin_amdgcn_global_load_lds(
        (const __attribute__((address_space(1))) void*)g,
        (__attribute__((address_space(3))) void*)l, 16, 0, 0);
}

__device__ inline bf16x8 ldsfrag(const u16* p) {
    u16x8 v = *(const u16x8*)p;
    return __builtin_bit_cast(bf16x8, v);
}

// ---------------------------------------------------------------------------
__global__ void zero_kernel(float* __restrict__ p, size_t n) {
    size_t i = (size_t)blockIdx.x * blockDim.x + threadIdx.x;
    size_t stride = (size_t)gridDim.x * blockDim.x;
    for (; i < n; i += stride) p[i] = 0.f;
}

__global__ void fill_adj_kernel(const int* __restrict__ edges, float* __restrict__ C) {
    int idx = blockIdx.x * blockDim.x + threadIdx.x;
    if (idx >= B * E) return;
    int b = idx / E;
    int e = idx - b * E;
    int src = edges[b * 2 * E + e];
    int dst = edges[b * 2 * E + E + e];
    atomicAdd(&C[(size_t)b * N * N + (size_t)dst * N + src], 1.0f);
}

__global__ void diag_kernel(float* __restrict__ C) {
    int idx = blockIdx.x * blockDim.x + threadIdx.x;
    if (idx >= B * N) return;
    C[(size_t)(idx >> 7) * N * N + (size_t)(idx & 127) * 129] += 1.0f;
}

__global__ void cbf_kernel(const float4* __restrict__ C4, ushort4* __restrict__ o, size_t n4) {
    size_t i = (size_t)blockIdx.x * blockDim.x + threadIdx.x;
    size_t stride = (size_t)gridDim.x * blockDim.x;
    for (; i < n4; i += stride) {
        float4 v = C4[i];
        ushort4 r;
        r.x = f2bf(v.x); r.y = f2bf(v.y); r.z = f2bf(v.z); r.w = f2bf(v.w);
        o[i] = r;
    }
}

// ---------------------------------------------------------------------------
// split x (fp32) -> hi/lo bf16 pair, LINEAR layout [b][n][k]
// ---------------------------------------------------------------------------
__global__ void split_kernel(const float4* __restrict__ x4,
                             uint2* __restrict__ hi4, uint2* __restrict__ lo4, size_t n4) {
    size_t i = (size_t)blockIdx.x * blockDim.x + threadIdx.x;
    size_t stride = (size_t)gridDim.x * blockDim.x;
    for (; i < n4; i += stride) {
        float4 v = x4[i];
        u16 h0 = f2bf(v.x), h1 = f2bf(v.y), h2 = f2bf(v.z), h3 = f2bf(v.w);
        uint2 hp; hp.x = (u32)h0 | ((u32)h1 << 16); hp.y = (u32)h2 | ((u32)h3 << 16);
        hi4[i] = hp;
        u16 l0 = f2bf(v.x - bf2f(h0)), l1 = f2bf(v.y - bf2f(h1));
        u16 l2 = f2bf(v.z - bf2f(h2)), l3 = f2bf(v.w - bf2f(h3));
        uint2 lp; lp.x = (u32)l0 | ((u32)l1 << 16); lp.y = (u32)l2 | ((u32)l3 << 16);
        lo4[i] = lp;
    }
}

// ---------------------------------------------------------------------------
// transpose+split W_cp[l][0:512][1024] fp32 -> Wt_hi/Wt_lo [l][1024 r][512 k]
// ---------------------------------------------------------------------------
__global__ __launch_bounds__(256)
void wt_split_kernel(const float* __restrict__ W_cp,
                     u16* __restrict__ Wt_hi, u16* __restrict__ Wt_lo) {
    __shared__ float t[64][65];
    const int l = blockIdx.z, k0 = blockIdx.y * 64, r0 = blockIdx.x * 64;
    const float* Wl = W_cp + (size_t)l * 513 * 1024;
    const int tx = threadIdx.x & 63, ty = threadIdx.x >> 6;
#pragma unroll
    for (int p = 0; p < 16; ++p) {
        int k = ty + p * 4;
        t[k][tx] = Wl[(size_t)(k0 + k) * 1024 + r0 + tx];
    }
    __syncthreads();
    u16* oh = Wt_hi + ((size_t)l * 1024 + r0) * 512 + k0;
    u16* ol = Wt_lo + ((size_t)l * 1024 + r0) * 512 + k0;
#pragma unroll
    for (int p = 0; p < 16; ++p) {
        int r = ty + p * 4;
        float v = t[tx][r];
        u16 hv = f2bf(v);
        oh[(size_t)r * 512 + tx] = hv;
        ol[(size_t)r * 512 + tx] = f2bf(v - bf2f(hv));
    }
}

// ---------------------------------------------------------------------------
// cp_pool, 256x256 block tile (2 batches x 256 r), 512 thr = 8 waves of
// 64x128. Single 64KB LDS buffer set, two-barrier K-loop with issue-after-B2
// DMA; the 96-MFMA burst (~2300cy) covers the 64KB staging (~1200cy).
// Per-MFMA operand traffic is HALF the 128x128 tile's -> past the L2 wall.
// ---------------------------------------------------------------------------
__global__ __launch_bounds__(512, 2)
void cp_pool_mfma_kernel(const u16* __restrict__ h_hi, const u16* __restrict__ h_lo,
                         const u16* __restrict__ Wt_hi, const u16* __restrict__ Wt_lo,
                         const float* __restrict__ Wbias,   // [1024] fp32 (W row 512)
                         float* __restrict__ prod_out)      // [B][R] this layer
{
    __shared__ u16 SS[4][256 * BK];     // Ah, Al, Bh, Bl : 16 KB each = 64 KB

    const int flat = blockIdx.x;        // 512 blocks
    const int xcd  = flat & 7;
    const int idx  = flat >> 3;
    const int bp   = xcd * 16 + (idx >> 2);   // batch pair 0..127
    const int r0   = (idx & 3) * 256;         // r tile

    const int tid  = threadIdx.x;
    const int w    = tid >> 6;          // 0..7
    const int lane = tid & 63;
    const int rb   = w & 3;             // row 64-group (0..3)
    const int cb   = w >> 2;            // col 128-group (0..1)

    floatx4 acc[4][8];
#pragma unroll
    for (int i = 0; i < 4; ++i)
#pragma unroll
        for (int j = 0; j < 8; ++j)
#pragma unroll
            for (int k = 0; k < 4; ++k) acc[i][j][k] = 0.f;

    // DMA staging: wave w stages rows [w*32, w*32+32) of each buffer,
    // 2 issues x 16 rows. lane: row = +(lane>>2), LDS chunk c=lane&3,
    // global chunk g = c ^ ((row>>1)&3) (xor swizzle, r4-proven).
    const int lrow = lane >> 2;
    const int g8   = (((lane & 3) ^ ((lane >> 3) & 3)) * 8);
    const u16* gA_h = h_hi  + ((size_t)bp * 256 + w * 32 + lrow) * 512 + g8;
    const u16* gA_l = h_lo  + ((size_t)bp * 256 + w * 32 + lrow) * 512 + g8;
    const u16* gB_h = Wt_hi + ((size_t)(r0 + w * 32 + lrow)) * 512 + g8;
    const u16* gB_l = Wt_lo + ((size_t)(r0 + w * 32 + lrow)) * 512 + g8;
    const int ldst = w * 1024 + lane * 8;     // + rr*32 for rr in {0,16}

    const int am = rb * 64 + (lane & 15);
    const int bn = cb * 128 + (lane & 15);
    const int ko = (((lane >> 4) ^ ((lane >> 1) & 3)) * 8);

#define DMASTEP(ks)                                                            \
    {                                                                          \
        const size_t go = (size_t)(ks) * BK;                                   \
        gload16(gA_h + go, &SS[0][ldst]);                                      \
        gload16(gA_h + go + 16 * 512, &SS[0][ldst + 512]);                     \
        gload16(gA_l + go, &SS[1][ldst]);                                      \
        gload16(gA_l + go + 16 * 512, &SS[1][ldst + 512]);                     \
        gload16(gB_h + go, &SS[2][ldst]);                                      \
        gload16(gB_h + go + 16 * 512, &SS[2][ldst + 512]);                     \
        gload16(gB_l + go, &SS[3][ldst]);                                      \
        gload16(gB_l + go + 16 * 512, &SS[3][ldst + 512]);                     \
    }

    DMASTEP(0)

    for (int ks = 0; ks < 16; ++ks) {
        __syncthreads();                 // B1: staging complete (vmcnt drain)

        bf16x8 ah[4], al[4], bh[8], bl[8];
#pragma unroll
        for (int t = 0; t < 4; ++t) {
            ah[t] = ldsfrag(&SS[0][(am + t * 16) * BK + ko]);
            al[t] = ldsfrag(&SS[1][(am + t * 16) * BK + ko]);
        }
#pragma unroll
        for (int t = 0; t < 8; ++t) {
            bh[t] = ldsfrag(&SS[2][(bn + t * 16) * BK + ko]);
            bl[t] = ldsfrag(&SS[3][(bn + t * 16) * BK + ko]);
        }
        __syncthreads();                 // B2: all reads done, buffers free

        if (ks < 15) DMASTEP(ks + 1)     // DMA flies under the MFMA burst

#pragma unroll
        for (int i = 0; i < 4; ++i)
#pragma unroll
            for (int j = 0; j < 8; ++j) {
                acc[i][j] = __builtin_amdgcn_mfma_f32_16x16x32_bf16(al[i], bh[j], acc[i][j], 0, 0, 0);
                acc[i][j] = __builtin_amdgcn_mfma_f32_16x16x32_bf16(ah[i], bl[j], acc[i][j], 0, 0, 0);
                acc[i][j] = __builtin_amdgcn_mfma_f32_16x16x32_bf16(ah[i], bh[j], acc[i][j], 0, 0, 0);
            }
    }
#undef DMASTEP

    // epilogue: +bias, tanh, product over n. red overlays SS (buffers dead).
    float* red = (float*)&SS[0][0];      // [4][256]
    const int quad = lane >> 4;
    const int c16  = lane & 15;
#pragma unroll
    for (int tj = 0; tj < 8; ++tj) {
        const int c = cb * 128 + tj * 16 + c16;
        const float bias = Wbias[r0 + c];
        float p = 1.f;
#pragma unroll
        for (int ti = 0; ti < 4; ++ti)
#pragma unroll
            for (int ri = 0; ri < 4; ++ri)
                p *= fast_tanh(acc[ti][tj][ri] + bias);
        p *= __shfl_xor(p, 16, 64);      // product over the 64 rows of this
        p *= __shfl_xor(p, 32, 64);      // wave's rb group
        if (quad == 0) red[rb * 256 + c] = p;
    }
    __syncthreads();
    {
        const int t    = tid & 255;
        const int half = tid >> 8;                  // 0: batch bp*2, 1: bp*2+1
        const int b    = bp * 2 + half;
        const float v  = red[(half * 2) * 256 + t] * red[(half * 2 + 1) * 256 + t];
        prod_out[(size_t)b * R + r0 + t] = v;
    }
}

// ---------------------------------------------------------------------------
// aggregate via MFMA: h_out = (C+I) @ h, LINEAR bf16 hi/lo in/out (round-4).
// ---------------------------------------------------------------------------
__global__ __launch_bounds__(256)
void aggregate_mfma_kernel(const u16* __restrict__ hi_in, const u16* __restrict__ lo_in,
                           const u16* __restrict__ Cbf,    // [B][128][128] bf16 (C+I)
                           u16* __restrict__ hi_out, u16* __restrict__ lo_out)
{
    __shared__ u16 Cs[128 * 32];
    __shared__ u16 Bs_hi[128 * 40];       // [d][s], stride 40
    __shared__ u16 Bs_lo[128 * 40];

    const int flat = blockIdx.x;
    const int rest = flat >> 3;
    const int b    = (flat & 7) * 32 + (rest >> 2);
    const int d0   = (rest & 3) * 128;

    const int tid  = threadIdx.x;
    const int w    = tid >> 6;
    const int lane = tid & 63;
    const int rb   = w & 1;
    const int cb   = w >> 1;

    floatx4 acc[4][4];
#pragma unroll
    for (int i = 0; i < 4; ++i)
#pragma unroll
        for (int j = 0; j < 4; ++j)
#pragma unroll
            for (int k = 0; k < 4; ++k) acc[i][j][k] = 0.f;

    const int kswz = (((lane & 3) ^ ((lane >> 3) & 3)) * 8);
    const u16* gC = Cbf + ((size_t)b * 128 + (w * 32 + (lane >> 2))) * 128 + kswz;

    const int ssi = tid >> 3;           // 0..31 (s within chunk)
    const int dg  = (tid & 7) * 16;     // 0..112
    const u16* gBh = hi_in + ((size_t)b * 128 + ssi) * 512 + d0 + dg;
    const u16* gBl = lo_in + ((size_t)b * 128 + ssi) * 512 + d0 + dg;

    const int am  = rb * 64 + (lane & 15);
    const int ko  = (((lane >> 4) ^ ((lane >> 1) & 3)) * 8);
    const int bko = (lane >> 4) * 8;

    for (int s0 = 0; s0 < 128; s0 += 32) {
#pragma unroll
        for (int it = 0; it < 2; ++it)
            gload16(gC + s0 + (size_t)it * 16 * 128, Cs + (w * 2 + it) * 512);

        {
            const u16* ph = gBh + (size_t)s0 * 512;
            const u16* pl = gBl + (size_t)s0 * 512;
            uint4 a0 = *(const uint4*)ph;
            uint4 a1 = *(const uint4*)(ph + 8);
            uint4 b0 = *(const uint4*)pl;
            uint4 b1 = *(const uint4*)(pl + 8);
            const u16* av0 = (const u16*)&a0; const u16* av1 = (const u16*)&a1;
            const u16* bv0 = (const u16*)&b0; const u16* bv1 = (const u16*)&b1;
#pragma unroll
            for (int i = 0; i < 8; ++i) {
                Bs_hi[(dg + i) * 40 + ssi]     = av0[i];
                Bs_hi[(dg + 8 + i) * 40 + ssi] = av1[i];
                Bs_lo[(dg + i) * 40 + ssi]     = bv0[i];
                Bs_lo[(dg + 8 + i) * 40 + ssi] = bv1[i];
            }
        }
        __syncthreads();

        bf16x8 af[4], bhf[4], blf[4];
#pragma unroll
        for (int t = 0; t < 4; ++t) {
            af[t]  = ldsfrag(&Cs[(am + t * 16) * 32 + ko]);
            const int d = cb * 64 + t * 16 + (lane & 15);
            bhf[t] = ldsfrag(&Bs_hi[d * 40 + bko]);
            blf[t] = ldsfrag(&Bs_lo[d * 40 + bko]);
        }
#pragma unroll
        for (int i = 0; i < 4; ++i)
#pragma unroll
            for (int j = 0; j < 4; ++j) {
                acc[i][j] = __builtin_amdgcn_mfma_f32_16x16x32_bf16(af[i], bhf[j], acc[i][j], 0, 0, 0);
                acc[i][j] = __builtin_amdgcn_mfma_f32_16x16x32_bf16(af[i], blf[j], acc[i][j], 0, 0, 0);
            }
        __syncthreads();
    }

    const int quad = lane >> 4;
    const int c16  = lane & 15;
#pragma unroll
    for (int i = 0; i < 4; ++i)
#pragma unroll
        for (int j = 0; j < 4; ++j) {
            const int d = d0 + cb * 64 + j * 16 + c16;
#pragma unroll
            for (int ri = 0; ri < 4; ++ri) {
                const int n = rb * 64 + i * 16 + quad * 4 + ri;
                size_t o = ((size_t)b * 128 + n) * 512 + d;
                float v = acc[i][j][ri];
                u16 hv = f2bf(v);
                hi_out[o] = hv;
                lo_out[o] = f2bf(v - bf2f(hv));
            }
        }
}

// ---------------------------------------------------------------------------
__global__ __launch_bounds__(256)
void score_kernel(const float* __restrict__ prod,   // [L,B,R]
                  const float* __restrict__ lin_w,  // [L,R,O]
                  const float* __restrict__ lin_b,  // [L,O]
                  float* __restrict__ out)          // [B,O]
{
    const int b   = blockIdx.x;
    const int tid = threadIdx.x;

    float acc[O];
#pragma unroll
    for (int o = 0; o < O; ++o) acc[o] = 0.f;

    for (int l = 0; l < L; ++l) {
        const float* pl = prod + ((size_t)l * B + b) * R;
        const float* wl = lin_w + (size_t)l * R * O;
        for (int r = tid; r < R; r += 256) {
            const float p = pl[r];
#pragma unroll
            for (int o = 0; o < O; ++o)
                acc[o] = fmaf(p, wl[r * O + o], acc[o]);
        }
    }

    __shared__ float sb[256];
    for (int o = 0; o < O; ++o) {
        sb[tid] = acc[o];
        __syncthreads();
        for (int off = 128; off > 0; off >>= 1) {
            if (tid < off) sb[tid] += sb[tid + off];
            __syncthreads();
        }
        if (tid == 0) {
            float bias = 0.f;
            for (int l = 0; l < L; ++l) bias += lin_b[l * O + o];
            out[b * O + o] = sb[0] + bias;
        }
        __syncthreads();
    }
}

// ---------------------------------------------------------------------------
extern "C" void kernel_launch(void* const* d_in, const int* in_sizes, int n_in,
                              void* d_out, int out_size, void* d_ws, size_t ws_size,
                              hipStream_t stream) {
    const float* x     = (const float*)d_in[0];   // [B,N,D]
    const int*   edges = (const int*)d_in[1];     // [B,2,E]
    const float* W_cp  = (const float*)d_in[2];   // [L,513,1024]
    const float* lin_w = (const float*)d_in[3];   // [L,R,O]
    const float* lin_b = (const float*)d_in[4];   // [L,O]
    float*       out   = (float*)d_out;           // [B,O]

    char* ws = (char*)d_ws;
    const size_t C_BYTES   = (size_t)B * N * N * 4;        // 16.8 MB
    const size_t CBF_BYTES = (size_t)B * N * N * 2;        // 8.4 MB
    const size_t HH_BYTES  = (size_t)B * N * D * 2;        // 33.6 MB
    const size_t WT_BYTES  = (size_t)L * 1024 * 512 * 2;   // 5.24 MB

    float* C     = (float*)ws;                    ws += C_BYTES;
    u16*   Cbf   = (u16*)ws;                      ws += CBF_BYTES;
    u16*   hiA   = (u16*)ws;                      ws += HH_BYTES;
    u16*   loA   = (u16*)ws;                      ws += HH_BYTES;
    u16*   hiB   = (u16*)ws;                      ws += HH_BYTES;
    u16*   loB   = (u16*)ws;                      ws += HH_BYTES;
    u16*   Wt_hi = (u16*)ws;                      ws += WT_BYTES;
    u16*   Wt_lo = (u16*)ws;                      ws += WT_BYTES;
    float* prod  = (float*)ws;                    // [L,B,R] 5.24 MB

    zero_kernel<<<1024, 256, 0, stream>>>(C, (size_t)B * N * N);
    fill_adj_kernel<<<(B * E + 255) / 256, 256, 0, stream>>>(edges, C);
    diag_kernel<<<(B * N + 255) / 256, 256, 0, stream>>>(C);
    cbf_kernel<<<1024, 256, 0, stream>>>((const float4*)C, (ushort4*)Cbf,
                                         (size_t)B * N * N / 4);
    wt_split_kernel<<<dim3(16, 8, L), 256, 0, stream>>>(W_cp, Wt_hi, Wt_lo);
    split_kernel<<<2048, 256, 0, stream>>>((const float4*)x, (uint2*)hiA, (uint2*)loA,
                                           (size_t)B * N * D / 4);

    // layer 0
    cp_pool_mfma_kernel<<<512, 512, 0, stream>>>(
        hiA, loA, Wt_hi, Wt_lo, W_cp + (size_t)512 * 1024, prod);

    const u16* phi = hiA; const u16* plo = loA;
    u16* bhi[2] = {hiB, hiA};
    u16* blo[2] = {loB, loA};
    for (int l = 1; l < L; ++l) {
        u16* nhi = bhi[(l - 1) & 1];
        u16* nlo = blo[(l - 1) & 1];
        aggregate_mfma_kernel<<<1024, 256, 0, stream>>>(phi, plo, Cbf, nhi, nlo);
        cp_pool_mfma_kernel<<<512, 512, 0, stream>>>(
            nhi, nlo,
            Wt_hi + (size_t)l * 1024 * 512, Wt_lo + (size_t)l * 1024 * 512,
            W_cp + ((size_t)l * 513 + 512) * 1024,
            prod + (size_t)l * B * R);
        phi = nhi; plo = nlo;
    }

    score_kernel<<<B, 256, 0, stream>>>(prod, lin_w, lin_b, out);
}

// Round 9
// 739.284 us; speedup vs baseline: 1.4373x; 1.0119x over previous
//
#include <hip/hip_runtime.h>
#include <math.h>

#define B 256
#define N 128
#define E 2048
#define D 512
#define R 1024
#define O 10
#define L 5
#define BK 32

typedef unsigned short u16;
typedef unsigned int u32;
typedef __bf16 bf16x8 __attribute__((ext_vector_type(8)));
typedef u16 u16x8 __attribute__((ext_vector_type(8)));
typedef float floatx4 __attribute__((ext_vector_type(4)));

// ---- bf16 helpers (RNE) ----------------------------------------------------
__device__ inline u16 f2bf(float f) {
    union { float f; u32 u; } v; v.f = f;
    u32 u = v.u;
    return (u16)((u + 0x7fffu + ((u >> 16) & 1u)) >> 16);
}
__device__ inline float bf2f(u16 s) {
    union { u32 u; float f; } v; v.u = ((u32)s) << 16;
    return v.f;
}

__device__ inline float fast_tanh(float x) {
    return 1.0f - 2.0f / (__expf(2.0f * x) + 1.0f);
}

// ---- async global->LDS, 16B per lane ---------------------------------------
__device__ inline void gload16(const void* g, void* l) {
    __builtin_amdgcn_global_load_lds(
        (const __attribute__((address_space(1))) void*)g,
        (__attribute__((address_space(3))) void*)l, 16, 0, 0);
}

__device__ inline bf16x8 ldsfrag(const u16* p) {
    u16x8 v = *(const u16x8*)p;
    return __builtin_bit_cast(bf16x8, v);
}

// ---------------------------------------------------------------------------
__global__ void zero_kernel(float* __restrict__ p, size_t n) {
    size_t i = (size_t)blockIdx.x * blockDim.x + threadIdx.x;
    size_t stride = (size_t)gridDim.x * blockDim.x;
    for (; i < n; i += stride) p[i] = 0.f;
}

__global__ void fill_adj_kernel(const int* __restrict__ edges, float* __restrict__ C) {
    int idx = blockIdx.x * blockDim.x + threadIdx.x;
    if (idx >= B * E) return;
    int b = idx / E;
    int e = idx - b * E;
    int src = edges[b * 2 * E + e];
    int dst = edges[b * 2 * E + E + e];
    atomicAdd(&C[(size_t)b * N * N + (size_t)dst * N + src], 1.0f);
}

__global__ void diag_kernel(float* __restrict__ C) {
    int idx = blockIdx.x * blockDim.x + threadIdx.x;
    if (idx >= B * N) return;
    C[(size_t)(idx >> 7) * N * N + (size_t)(idx & 127) * 129] += 1.0f;
}

__global__ void cbf_kernel(const float4* __restrict__ C4, ushort4* __restrict__ o, size_t n4) {
    size_t i = (size_t)blockIdx.x * blockDim.x + threadIdx.x;
    size_t stride = (size_t)gridDim.x * blockDim.x;
    for (; i < n4; i += stride) {
        float4 v = C4[i];
        ushort4 r;
        r.x = f2bf(v.x); r.y = f2bf(v.y); r.z = f2bf(v.z); r.w = f2bf(v.w);
        o[i] = r;
    }
}

// ---------------------------------------------------------------------------
// split x (fp32) -> hi/lo bf16 pair, LINEAR layout [b][n][k]
// ---------------------------------------------------------------------------
__global__ void split_kernel(const float4* __restrict__ x4,
                             uint2* __restrict__ hi4, uint2* __restrict__ lo4, size_t n4) {
    size_t i = (size_t)blockIdx.x * blockDim.x + threadIdx.x;
    size_t stride = (size_t)gridDim.x * blockDim.x;
    for (; i < n4; i += stride) {
        float4 v = x4[i];
        u16 h0 = f2bf(v.x), h1 = f2bf(v.y), h2 = f2bf(v.z), h3 = f2bf(v.w);
        uint2 hp; hp.x = (u32)h0 | ((u32)h1 << 16); hp.y = (u32)h2 | ((u32)h3 << 16);
        hi4[i] = hp;
        u16 l0 = f2bf(v.x - bf2f(h0)), l1 = f2bf(v.y - bf2f(h1));
        u16 l2 = f2bf(v.z - bf2f(h2)), l3 = f2bf(v.w - bf2f(h3));
        uint2 lp; lp.x = (u32)l0 | ((u32)l1 << 16); lp.y = (u32)l2 | ((u32)l3 << 16);
        lo4[i] = lp;
    }
}

// ---------------------------------------------------------------------------
// transpose+split W_cp[l][0:512][1024] fp32 -> Wt_hi/Wt_lo [l][1024 r][512 k]
// ---------------------------------------------------------------------------
__global__ __launch_bounds__(256)
void wt_split_kernel(const float* __restrict__ W_cp,
                     u16* __restrict__ Wt_hi, u16* __restrict__ Wt_lo) {
    __shared__ float t[64][65];
    const int l = blockIdx.z, k0 = blockIdx.y * 64, r0 = blockIdx.x * 64;
    const float* Wl = W_cp + (size_t)l * 513 * 1024;
    const int tx = threadIdx.x & 63, ty = threadIdx.x >> 6;
#pragma unroll
    for (int p = 0; p < 16; ++p) {
        int k = ty + p * 4;
        t[k][tx] = Wl[(size_t)(k0 + k) * 1024 + r0 + tx];
    }
    __syncthreads();
    u16* oh = Wt_hi + ((size_t)l * 1024 + r0) * 512 + k0;
    u16* ol = Wt_lo + ((size_t)l * 1024 + r0) * 512 + k0;
#pragma unroll
    for (int p = 0; p < 16; ++p) {
        int r = ty + p * 4;
        float v = t[tx][r];
        u16 hv = f2bf(v);
        oh[(size_t)r * 512 + tx] = hv;
        ol[(size_t)r * 512 + tx] = f2bf(v - bf2f(hv));
    }
}

// ---------------------------------------------------------------------------
// cp_pool, 256x256 tile, DOUBLE-BUFFERED 128KB dynamic LDS, one barrier/step:
//   barrier (drains DMA into buf p, issued a full step ago)
//   -> issue DMA(ks+1) into buf 1-p  -> ds_read frags from p  -> 96-MFMA burst
// No B2 lockstep: ds_reads interleave with MFMAs (fine lgkmcnt), LDS pipe
// hides under the MFMA burst.
// ---------------------------------------------------------------------------
__global__ __launch_bounds__(512, 2)
void cp_pool_mfma_kernel(const u16* __restrict__ h_hi, const u16* __restrict__ h_lo,
                         const u16* __restrict__ Wt_hi, const u16* __restrict__ Wt_lo,
                         const float* __restrict__ Wbias,   // [1024] fp32 (W row 512)
                         float* __restrict__ prod_out)      // [B][R] this layer
{
    extern __shared__ u16 SS[];          // [2][4][256*BK] = 128 KB
    // buffer p at SS + p*32768; operand q at +q*8192

    const int flat = blockIdx.x;        // 512 blocks
    const int xcd  = flat & 7;
    const int idx  = flat >> 3;
    const int bp   = xcd * 16 + (idx >> 2);   // batch pair 0..127
    const int r0   = (idx & 3) * 256;         // r tile

    const int tid  = threadIdx.x;
    const int w    = tid >> 6;          // 0..7
    const int lane = tid & 63;
    const int rb   = w & 3;             // row 64-group (0..3)
    const int cb   = w >> 2;            // col 128-group (0..1)

    floatx4 acc[4][8];
#pragma unroll
    for (int i = 0; i < 4; ++i)
#pragma unroll
        for (int j = 0; j < 8; ++j)
#pragma unroll
            for (int k = 0; k < 4; ++k) acc[i][j][k] = 0.f;

    // DMA staging: wave w stages rows [w*32, w*32+32), xor-chunk swizzle.
    const int lrow = lane >> 2;
    const int g8   = (((lane & 3) ^ ((lane >> 3) & 3)) * 8);
    const u16* gA_h = h_hi  + ((size_t)bp * 256 + w * 32 + lrow) * 512 + g8;
    const u16* gA_l = h_lo  + ((size_t)bp * 256 + w * 32 + lrow) * 512 + g8;
    const u16* gB_h = Wt_hi + ((size_t)(r0 + w * 32 + lrow)) * 512 + g8;
    const u16* gB_l = Wt_lo + ((size_t)(r0 + w * 32 + lrow)) * 512 + g8;
    const int ldst = w * 1024 + lane * 8;

    const int am = rb * 64 + (lane & 15);
    const int bn = cb * 128 + (lane & 15);
    const int ko = (((lane >> 4) ^ ((lane >> 1) & 3)) * 8);

#define DMASTEP(ks, bufofs)                                                    \
    {                                                                          \
        const size_t go = (size_t)(ks) * BK;                                   \
        gload16(gA_h + go,            &SS[(bufofs) + 0 * 8192 + ldst]);        \
        gload16(gA_h + go + 16 * 512, &SS[(bufofs) + 0 * 8192 + ldst + 512]);  \
        gload16(gA_l + go,            &SS[(bufofs) + 1 * 8192 + ldst]);        \
        gload16(gA_l + go + 16 * 512, &SS[(bufofs) + 1 * 8192 + ldst + 512]);  \
        gload16(gB_h + go,            &SS[(bufofs) + 2 * 8192 + ldst]);        \
        gload16(gB_h + go + 16 * 512, &SS[(bufofs) + 2 * 8192 + ldst + 512]);  \
        gload16(gB_l + go,            &SS[(bufofs) + 3 * 8192 + ldst]);        \
        gload16(gB_l + go + 16 * 512, &SS[(bufofs) + 3 * 8192 + ldst + 512]);  \
    }

    DMASTEP(0, 0)

#pragma unroll
    for (int ks = 0; ks < 16; ++ks) {
        const int po = (ks & 1) * 32768;        // this step's buffer
        __syncthreads();   // drains DMA(ks) [full step in flight] + prior reads

        if (ks < 15) DMASTEP(ks + 1, 32768 - po)   // into the other buffer

        const u16* S0 = &SS[po];
        bf16x8 ah[4], al[4], bh[8], bl[8];
#pragma unroll
        for (int t = 0; t < 4; ++t) {
            ah[t] = ldsfrag(&S0[0 * 8192 + (am + t * 16) * BK + ko]);
            al[t] = ldsfrag(&S0[1 * 8192 + (am + t * 16) * BK + ko]);
        }
#pragma unroll
        for (int t = 0; t < 8; ++t) {
            bh[t] = ldsfrag(&S0[2 * 8192 + (bn + t * 16) * BK + ko]);
            bl[t] = ldsfrag(&S0[3 * 8192 + (bn + t * 16) * BK + ko]);
        }

#pragma unroll
        for (int i = 0; i < 4; ++i)
#pragma unroll
            for (int j = 0; j < 8; ++j) {
                acc[i][j] = __builtin_amdgcn_mfma_f32_16x16x32_bf16(al[i], bh[j], acc[i][j], 0, 0, 0);
                acc[i][j] = __builtin_amdgcn_mfma_f32_16x16x32_bf16(ah[i], bl[j], acc[i][j], 0, 0, 0);
                acc[i][j] = __builtin_amdgcn_mfma_f32_16x16x32_bf16(ah[i], bh[j], acc[i][j], 0, 0, 0);
            }
    }
#undef DMASTEP

    // epilogue: +bias, tanh, product over n. red overlays buffer 0 (last-read
    // buffer was p=1, so buffer 0 is dead).
    float* red = (float*)&SS[0];         // [4][256] floats = 4 KB
    const int quad = lane >> 4;
    const int c16  = lane & 15;
#pragma unroll
    for (int tj = 0; tj < 8; ++tj) {
        const int c = cb * 128 + tj * 16 + c16;
        const float bias = Wbias[r0 + c];
        float p = 1.f;
#pragma unroll
        for (int ti = 0; ti < 4; ++ti)
#pragma unroll
            for (int ri = 0; ri < 4; ++ri)
                p *= fast_tanh(acc[ti][tj][ri] + bias);
        p *= __shfl_xor(p, 16, 64);
        p *= __shfl_xor(p, 32, 64);
        if (quad == 0) red[rb * 256 + c] = p;
    }
    __syncthreads();
    {
        const int t    = tid & 255;
        const int half = tid >> 8;                  // 0: batch bp*2, 1: bp*2+1
        const int b    = bp * 2 + half;
        const float v  = red[(half * 2) * 256 + t] * red[(half * 2 + 1) * 256 + t];
        prod_out[(size_t)b * R + r0 + t] = v;
    }
}

// ---------------------------------------------------------------------------
// aggregate via MFMA: h_out = (C+I) @ h, LINEAR bf16 hi/lo in/out (round-4).
// ---------------------------------------------------------------------------
__global__ __launch_bounds__(256)
void aggregate_mfma_kernel(const u16* __restrict__ hi_in, const u16* __restrict__ lo_in,
                           const u16* __restrict__ Cbf,    // [B][128][128] bf16 (C+I)
                           u16* __restrict__ hi_out, u16* __restrict__ lo_out)
{
    __shared__ u16 Cs[128 * 32];
    __shared__ u16 Bs_hi[128 * 40];       // [d][s], stride 40
    __shared__ u16 Bs_lo[128 * 40];

    const int flat = blockIdx.x;
    const int rest = flat >> 3;
    const int b    = (flat & 7) * 32 + (rest >> 2);
    const int d0   = (rest & 3) * 128;

    const int tid  = threadIdx.x;
    const int w    = tid >> 6;
    const int lane = tid & 63;
    const int rb   = w & 1;
    const int cb   = w >> 1;

    floatx4 acc[4][4];
#pragma unroll
    for (int i = 0; i < 4; ++i)
#pragma unroll
        for (int j = 0; j < 4; ++j)
#pragma unroll
            for (int k = 0; k < 4; ++k) acc[i][j][k] = 0.f;

    const int kswz = (((lane & 3) ^ ((lane >> 3) & 3)) * 8);
    const u16* gC = Cbf + ((size_t)b * 128 + (w * 32 + (lane >> 2))) * 128 + kswz;

    const int ssi = tid >> 3;           // 0..31 (s within chunk)
    const int dg  = (tid & 7) * 16;     // 0..112
    const u16* gBh = hi_in + ((size_t)b * 128 + ssi) * 512 + d0 + dg;
    const u16* gBl = lo_in + ((size_t)b * 128 + ssi) * 512 + d0 + dg;

    const int am  = rb * 64 + (lane & 15);
    const int ko  = (((lane >> 4) ^ ((lane >> 1) & 3)) * 8);
    const int bko = (lane >> 4) * 8;

    for (int s0 = 0; s0 < 128; s0 += 32) {
#pragma unroll
        for (int it = 0; it < 2; ++it)
            gload16(gC + s0 + (size_t)it * 16 * 128, Cs + (w * 2 + it) * 512);

        {
            const u16* ph = gBh + (size_t)s0 * 512;
            const u16* pl = gBl + (size_t)s0 * 512;
            uint4 a0 = *(const uint4*)ph;
            uint4 a1 = *(const uint4*)(ph + 8);
            uint4 b0 = *(const uint4*)pl;
            uint4 b1 = *(const uint4*)(pl + 8);
            const u16* av0 = (const u16*)&a0; const u16* av1 = (const u16*)&a1;
            const u16* bv0 = (const u16*)&b0; const u16* bv1 = (const u16*)&b1;
#pragma unroll
            for (int i = 0; i < 8; ++i) {
                Bs_hi[(dg + i) * 40 + ssi]     = av0[i];
                Bs_hi[(dg + 8 + i) * 40 + ssi] = av1[i];
                Bs_lo[(dg + i) * 40 + ssi]     = bv0[i];
                Bs_lo[(dg + 8 + i) * 40 + ssi] = bv1[i];
            }
        }
        __syncthreads();

        bf16x8 af[4], bhf[4], blf[4];
#pragma unroll
        for (int t = 0; t < 4; ++t) {
            af[t]  = ldsfrag(&Cs[(am + t * 16) * 32 + ko]);
            const int d = cb * 64 + t * 16 + (lane & 15);
            bhf[t] = ldsfrag(&Bs_hi[d * 40 + bko]);
            blf[t] = ldsfrag(&Bs_lo[d * 40 + bko]);
        }
#pragma unroll
        for (int i = 0; i < 4; ++i)
#pragma unroll
            for (int j = 0; j < 4; ++j) {
                acc[i][j] = __builtin_amdgcn_mfma_f32_16x16x32_bf16(af[i], bhf[j], acc[i][j], 0, 0, 0);
                acc[i][j] = __builtin_amdgcn_mfma_f32_16x16x32_bf16(af[i], blf[j], acc[i][j], 0, 0, 0);
            }
        __syncthreads();
    }

    const int quad = lane >> 4;
    const int c16  = lane & 15;
#pragma unroll
    for (int i = 0; i < 4; ++i)
#pragma unroll
        for (int j = 0; j < 4; ++j) {
            const int d = d0 + cb * 64 + j * 16 + c16;
#pragma unroll
            for (int ri = 0; ri < 4; ++ri) {
                const int n = rb * 64 + i * 16 + quad * 4 + ri;
                size_t o = ((size_t)b * 128 + n) * 512 + d;
                float v = acc[i][j][ri];
                u16 hv = f2bf(v);
                hi_out[o] = hv;
                lo_out[o] = f2bf(v - bf2f(hv));
            }
        }
}

// ---------------------------------------------------------------------------
__global__ __launch_bounds__(256)
void score_kernel(const float* __restrict__ prod,   // [L,B,R]
                  const float* __restrict__ lin_w,  // [L,R,O]
                  const float* __restrict__ lin_b,  // [L,O]
                  float* __restrict__ out)          // [B,O]
{
    const int b   = blockIdx.x;
    const int tid = threadIdx.x;

    float acc[O];
#pragma unroll
    for (int o = 0; o < O; ++o) acc[o] = 0.f;

    for (int l = 0; l < L; ++l) {
        const float* pl = prod + ((size_t)l * B + b) * R;
        const float* wl = lin_w + (size_t)l * R * O;
        for (int r = tid; r < R; r += 256) {
            const float p = pl[r];
#pragma unroll
            for (int o = 0; o < O; ++o)
                acc[o] = fmaf(p, wl[r * O + o], acc[o]);
        }
    }

    __shared__ float sb[256];
    for (int o = 0; o < O; ++o) {
        sb[tid] = acc[o];
        __syncthreads();
        for (int off = 128; off > 0; off >>= 1) {
            if (tid < off) sb[tid] += sb[tid + off];
            __syncthreads();
        }
        if (tid == 0) {
            float bias = 0.f;
            for (int l = 0; l < L; ++l) bias += lin_b[l * O + o];
            out[b * O + o] = sb[0] + bias;
        }
        __syncthreads();
    }
}

// ---------------------------------------------------------------------------
extern "C" void kernel_launch(void* const* d_in, const int* in_sizes, int n_in,
                              void* d_out, int out_size, void* d_ws, size_t ws_size,
                              hipStream_t stream) {
    const float* x     = (const float*)d_in[0];   // [B,N,D]
    const int*   edges = (const int*)d_in[1];     // [B,2,E]
    const float* W_cp  = (const float*)d_in[2];   // [L,513,1024]
    const float* lin_w = (const float*)d_in[3];   // [L,R,O]
    const float* lin_b = (const float*)d_in[4];   // [L,O]
    float*       out   = (float*)d_out;           // [B,O]

    char* ws = (char*)d_ws;
    const size_t C_BYTES   = (size_t)B * N * N * 4;        // 16.8 MB
    const size_t CBF_BYTES = (size_t)B * N * N * 2;        // 8.4 MB
    const size_t HH_BYTES  = (size_t)B * N * D * 2;        // 33.6 MB
    const size_t WT_BYTES  = (size_t)L * 1024 * 512 * 2;   // 5.24 MB

    float* C     = (float*)ws;                    ws += C_BYTES;
    u16*   Cbf   = (u16*)ws;                      ws += CBF_BYTES;
    u16*   hiA   = (u16*)ws;                      ws += HH_BYTES;
    u16*   loA   = (u16*)ws;                      ws += HH_BYTES;
    u16*   hiB   = (u16*)ws;                      ws += HH_BYTES;
    u16*   loB   = (u16*)ws;                      ws += HH_BYTES;
    u16*   Wt_hi = (u16*)ws;                      ws += WT_BYTES;
    u16*   Wt_lo = (u16*)ws;                      ws += WT_BYTES;
    float* prod  = (float*)ws;                    // [L,B,R] 5.24 MB

    // allow 128 KB dynamic LDS for the double-buffered GEMM (idempotent)
    (void)hipFuncSetAttribute((const void*)cp_pool_mfma_kernel,
                              hipFuncAttributeMaxDynamicSharedMemorySize, 131072);

    zero_kernel<<<1024, 256, 0, stream>>>(C, (size_t)B * N * N);
    fill_adj_kernel<<<(B * E + 255) / 256, 256, 0, stream>>>(edges, C);
    diag_kernel<<<(B * N + 255) / 256, 256, 0, stream>>>(C);
    cbf_kernel<<<1024, 256, 0, stream>>>((const float4*)C, (ushort4*)Cbf,
                                         (size_t)B * N * N / 4);
    wt_split_kernel<<<dim3(16, 8, L), 256, 0, stream>>>(W_cp, Wt_hi, Wt_lo);
    split_kernel<<<2048, 256, 0, stream>>>((const float4*)x, (uint2*)hiA, (uint2*)loA,
                                           (size_t)B * N * D / 4);

    // layer 0
    cp_pool_mfma_kernel<<<512, 512, 131072, stream>>>(
        hiA, loA, Wt_hi, Wt_lo, W_cp + (size_t)512 * 1024, prod);

    const u16* phi = hiA; const u16* plo = loA;
    u16* bhi[2] = {hiB, hiA};
    u16* blo[2] = {loB, loA};
    for (int l = 1; l < L; ++l) {
        u16* nhi = bhi[(l - 1) & 1];
        u16* nlo = blo[(l - 1) & 1];
        aggregate_mfma_kernel<<<1024, 256, 0, stream>>>(phi, plo, Cbf, nhi, nlo);
        cp_pool_mfma_kernel<<<512, 512, 131072, stream>>>(
            nhi, nlo,
            Wt_hi + (size_t)l * 1024 * 512, Wt_lo + (size_t)l * 1024 * 512,
            W_cp + ((size_t)l * 513 + 512) * 1024,
            prod + (size_t)l * B * R);
        phi = nhi; plo = nlo;
    }

    score_kernel<<<B, 256, 0, stream>>>(prod, lin_w, lin_b, out);
}